// Round 1
// baseline (858.629 us; speedup 1.0000x reference)
//
#include <hip/hip_runtime.h>

// LightGCN extractor: 3-layer propagation over 150K nodes / 1.2M edges, D=64.
// Baseline: atomic scatter-add per edge (wave-per-edge, lane-per-dim).

#define STU 100000
#define EXER 50000
#define KNOW 123
#define DIM 64
#define N_NODES 150000
#define N_EDGES 1200000

static const long long NODE_F = (long long)N_NODES * DIM;          // 9,600,000 floats
static const size_t NODE_BYTES = (size_t)NODE_F * sizeof(float);   // 38,400,000 bytes

__device__ __forceinline__ void atomAddF(float* p, float v) {
    // HW global_atomic_add_f32 on gfx950 (avoids CAS loop)
    unsafeAtomicAdd(p, v);
}

// Layer 1: h0 is the virtual concat [stu_emb; exer_emb], read directly from inputs.
__global__ void k_scatter_l0(const int* __restrict__ erow, const int* __restrict__ ecol,
                             const float* __restrict__ eval,
                             const float* __restrict__ stu, const float* __restrict__ exer,
                             float* __restrict__ out) {
    long long t = (long long)blockIdx.x * blockDim.x + threadIdx.x;
    if (t >= (long long)N_EDGES * DIM) return;
    int e = (int)(t >> 6);
    int d = (int)(t & 63);
    int r = erow[e];
    int c = ecol[e];
    float v = eval[e];
    float hv = (c < STU) ? stu[(long long)c * DIM + d]
                         : exer[(long long)(c - STU) * DIM + d];
    atomAddF(out + (long long)r * DIM + d, v * hv);
}

// Layers 2,3: read from a full node-table buffer.
__global__ void k_scatter(const int* __restrict__ erow, const int* __restrict__ ecol,
                          const float* __restrict__ eval,
                          const float* __restrict__ h, float* __restrict__ out) {
    long long t = (long long)blockIdx.x * blockDim.x + threadIdx.x;
    if (t >= (long long)N_EDGES * DIM) return;
    int e = (int)(t >> 6);
    int d = (int)(t & 63);
    int r = erow[e];
    int c = ecol[e];
    float v = eval[e];
    float hv = h[(long long)c * DIM + d];
    atomAddF(out + (long long)r * DIM + d, v * hv);
}

// acc = h0 + h1   (float4 elementwise; STU*DIM = 6.4M is divisible by 4)
__global__ void k_acc_init(const float* __restrict__ stu, const float* __restrict__ exer,
                           const float* __restrict__ h1, float* __restrict__ acc) {
    long long i = (long long)blockIdx.x * blockDim.x + threadIdx.x;  // float4 index
    long long n4 = NODE_F >> 2;
    if (i >= n4) return;
    long long stu4 = ((long long)STU * DIM) >> 2;
    const float4* h14 = (const float4*)h1;
    float4* acc4 = (float4*)acc;
    float4 h0 = (i < stu4) ? ((const float4*)stu)[i]
                           : ((const float4*)exer)[i - stu4];
    float4 a = h14[i];
    a.x += h0.x; a.y += h0.y; a.z += h0.z; a.w += h0.w;
    acc4[i] = a;
}

// acc += h   (float4 elementwise)
__global__ void k_acc_add(float* __restrict__ acc, const float* __restrict__ h) {
    long long i = (long long)blockIdx.x * blockDim.x + threadIdx.x;
    long long n4 = NODE_F >> 2;
    if (i >= n4) return;
    float4* acc4 = (float4*)acc;
    const float4* h4 = (const float4*)h;
    float4 a = acc4[i];
    float4 b = h4[i];
    a.x += b.x; a.y += b.y; a.z += b.z; a.w += b.w;
    acc4[i] = a;
}

// Outputs, flat-concatenated:
//   [0, 524288)          student_ts = (acc/4)[student_id]
//   [524288, 1048576)    diff_ts    = (acc/4)[STU + exercise_id]
//   [1048576, 1056768)   disc_ts    = disc_emb[exercise_id]
//   [1056768, 1064640)   knowledge  = know_emb
__global__ void k_outputs(const int* __restrict__ sid, const int* __restrict__ eid,
                          const float* __restrict__ disc, const float* __restrict__ know,
                          const float* __restrict__ acc, float* __restrict__ out) {
    int idx = blockIdx.x * blockDim.x + threadIdx.x;
    if (idx < 524288) {
        int i = idx >> 6, d = idx & 63;
        out[idx] = acc[(long long)sid[i] * DIM + d] * 0.25f;
    } else if (idx < 1048576) {
        int j = idx - 524288;
        int i = j >> 6, d = j & 63;
        out[idx] = acc[((long long)STU + eid[i]) * DIM + d] * 0.25f;
    } else if (idx < 1056768) {
        int i = idx - 1048576;
        out[idx] = disc[eid[i]];
    } else if (idx < 1064640) {
        out[idx] = know[idx - 1056768];
    }
}

extern "C" void kernel_launch(void* const* d_in, const int* in_sizes, int n_in,
                              void* d_out, int out_size, void* d_ws, size_t ws_size,
                              hipStream_t stream) {
    const int*   sid  = (const int*)d_in[0];
    const int*   eid  = (const int*)d_in[1];
    // d_in[2] = q_mask (unused by reference outputs)
    const int*   erow = (const int*)d_in[3];
    const int*   ecol = (const int*)d_in[4];
    const float* eval = (const float*)d_in[5];
    const float* stu  = (const float*)d_in[6];
    const float* exer = (const float*)d_in[7];
    const float* disc = (const float*)d_in[8];
    const float* know = (const float*)d_in[9];
    float* out = (float*)d_out;

    char* ws = (char*)d_ws;
    float* A = (float*)(ws);                      // layer buffer (ping)
    float* B = (float*)(ws + NODE_BYTES);         // layer buffer (pong)
    float* C = (float*)(ws + 2 * NODE_BYTES);     // running accumulator
    // needs ws_size >= 115,200,000 bytes

    const int BLK = 256;
    long long edgeThreads = (long long)N_EDGES * DIM;          // 76.8M
    int edgeGrid = (int)((edgeThreads + BLK - 1) / BLK);       // 300000
    long long n4 = NODE_F >> 2;                                // 2.4M
    int eltGrid = (int)((n4 + BLK - 1) / BLK);                 // 9375
    int outGrid = (1064640 + BLK - 1) / BLK;

    // Layer 1: A = segsum(val * h0[col])
    hipMemsetAsync(A, 0, NODE_BYTES, stream);
    k_scatter_l0<<<edgeGrid, BLK, 0, stream>>>(erow, ecol, eval, stu, exer, A);
    // C = h0 + h1
    k_acc_init<<<eltGrid, BLK, 0, stream>>>(stu, exer, A, C);

    // Layer 2: B = segsum(val * A[col]); C += B
    hipMemsetAsync(B, 0, NODE_BYTES, stream);
    k_scatter<<<edgeGrid, BLK, 0, stream>>>(erow, ecol, eval, A, B);
    k_acc_add<<<eltGrid, BLK, 0, stream>>>(C, B);

    // Layer 3: A = segsum(val * B[col]); C += A
    hipMemsetAsync(A, 0, NODE_BYTES, stream);
    k_scatter<<<edgeGrid, BLK, 0, stream>>>(erow, ecol, eval, B, A);
    k_acc_add<<<eltGrid, BLK, 0, stream>>>(C, A);

    // Outputs
    k_outputs<<<outGrid, BLK, 0, stream>>>(sid, eid, disc, know, C, out);
}

// Round 2
// 412.794 us; speedup vs baseline: 2.0800x; 2.0800x over previous
//
#include <hip/hip_runtime.h>

// LightGCN extractor, round 2: CSR-gather segment-sum (no float atomics).
// Per call: build CSR (hist -> scan -> fill), 2 full gather layers,
// layer 3 fused into the output kernel (only ~16K rows needed).

#define STU 100000
#define EXER 50000
#define KNOW 123
#define DIM 64
#define N_NODES 150000
#define N_EDGES 1200000
#define NB 8192              // batch size for sid/eid
#define NSCAN_BLOCKS 586     // ceil(150000/256)

static const long long NODE_F = (long long)N_NODES * DIM;          // 9.6M floats
static const size_t NODE_BYTES = (size_t)NODE_F * sizeof(float);   // 38.4 MB

// ---- CSR build ----

__global__ void k_hist(const int* __restrict__ erow, int* __restrict__ deg) {
    int e = blockIdx.x * blockDim.x + threadIdx.x;
    if (e < N_EDGES) atomicAdd(&deg[erow[e]], 1);
}

__global__ void k_scan1(const int* __restrict__ deg, int* __restrict__ off,
                        int* __restrict__ bsum) {
    __shared__ int s[256];
    int i = blockIdx.x * 256 + threadIdx.x;
    int v = (i < N_NODES) ? deg[i] : 0;
    s[threadIdx.x] = v;
    __syncthreads();
    for (int o = 1; o < 256; o <<= 1) {
        int x = (threadIdx.x >= o) ? s[threadIdx.x - o] : 0;
        __syncthreads();
        s[threadIdx.x] += x;
        __syncthreads();
    }
    if (i < N_NODES) off[i] = s[threadIdx.x] - v;     // exclusive within block
    if (threadIdx.x == 255) bsum[blockIdx.x] = s[255];
}

__global__ void k_scan2(const int* __restrict__ bsum, int* __restrict__ bsumoff) {
    __shared__ int s[1024];
    int t = threadIdx.x;
    int v = (t < NSCAN_BLOCKS) ? bsum[t] : 0;
    s[t] = v;
    __syncthreads();
    for (int o = 1; o < 1024; o <<= 1) {
        int x = (t >= o) ? s[t - o] : 0;
        __syncthreads();
        s[t] += x;
        __syncthreads();
    }
    if (t < NSCAN_BLOCKS) bsumoff[t] = s[t] - v;      // exclusive across blocks
}

__global__ void k_scan3(int* __restrict__ off, int* __restrict__ cur,
                        const int* __restrict__ bsumoff) {
    int i = blockIdx.x * 256 + threadIdx.x;
    if (i < N_NODES) {
        int v = off[i] + bsumoff[i >> 8];
        off[i] = v;
        cur[i] = v;
    }
    if (i == 0) off[N_NODES] = N_EDGES;
}

__global__ void k_fill(const int* __restrict__ erow, const int* __restrict__ ecol,
                       const float* __restrict__ eval,
                       int* __restrict__ cur, int2* __restrict__ sedge) {
    int e = blockIdx.x * blockDim.x + threadIdx.x;
    if (e < N_EDGES) {
        int r = erow[e];
        int p = atomicAdd(&cur[r], 1);
        sedge[p] = make_int2(ecol[e], __float_as_int(eval[e]));
    }
}

// ---- gather layers: wave per node, lane per dim ----

__global__ void k_gather_l1(const int* __restrict__ off, const int2* __restrict__ sedge,
                            const float* __restrict__ stu, const float* __restrict__ exer,
                            float* __restrict__ out) {
    int w = (blockIdx.x * blockDim.x + threadIdx.x) >> 6;
    int lane = threadIdx.x & 63;
    if (w >= N_NODES) return;
    int s = off[w], e = off[w + 1];
    float acc = 0.f;
    for (int k = s; k < e; k++) {
        int2 ev = sedge[k];
        int c = ev.x;
        float v = __int_as_float(ev.y);
        float hv = (c < STU) ? stu[(long long)c * DIM + lane]
                             : exer[(long long)(c - STU) * DIM + lane];
        acc += v * hv;
    }
    out[(long long)w * DIM + lane] = acc;
}

__global__ void k_gather(const int* __restrict__ off, const int2* __restrict__ sedge,
                         const float* __restrict__ h, float* __restrict__ out) {
    int w = (blockIdx.x * blockDim.x + threadIdx.x) >> 6;
    int lane = threadIdx.x & 63;
    if (w >= N_NODES) return;
    int s = off[w], e = off[w + 1];
    float acc = 0.f;
    for (int k = s; k < e; k++) {
        int2 ev = sedge[k];
        acc += __int_as_float(ev.y) * h[(long long)ev.x * DIM + lane];
    }
    out[(long long)w * DIM + lane] = acc;
}

// ---- outputs: layer-3 gather fused, only at the 16K needed rows ----
// out layout: [0,524288) student_ts | [524288,1048576) diff_ts
//             [1048576,1056768) disc | [1056768,1064640) know

__global__ void k_out_main(const int* __restrict__ sid, const int* __restrict__ eid,
                           const int* __restrict__ off, const int2* __restrict__ sedge,
                           const float* __restrict__ stu, const float* __restrict__ exer,
                           const float* __restrict__ A, const float* __restrict__ B,
                           float* __restrict__ out) {
    int w = (blockIdx.x * blockDim.x + threadIdx.x) >> 6;
    int lane = threadIdx.x & 63;
    if (w >= 2 * NB) return;
    int r;
    long long obase;
    if (w < NB) { r = sid[w];             obase = (long long)w * 64; }
    else        { r = STU + eid[w - NB];  obase = 524288 + (long long)(w - NB) * 64; }
    long long rb = (long long)r * 64 + lane;
    float h0 = (r < STU) ? stu[rb] : exer[rb - (long long)STU * 64];
    float s = h0 + A[rb] + B[rb];
    int st = off[r], en = off[r + 1];
    float g = 0.f;
    for (int k = st; k < en; k++) {
        int2 ev = sedge[k];
        g += __int_as_float(ev.y) * B[(long long)ev.x * DIM + lane];
    }
    out[obase + lane] = 0.25f * (s + g);
}

__global__ void k_out_tail(const int* __restrict__ eid, const float* __restrict__ disc,
                           const float* __restrict__ know, float* __restrict__ out) {
    int i = blockIdx.x * blockDim.x + threadIdx.x;
    if (i < NB) out[1048576 + i] = disc[eid[i]];
    else if (i < NB + KNOW * DIM) out[1056768 + (i - NB)] = know[i - NB];
}

extern "C" void kernel_launch(void* const* d_in, const int* in_sizes, int n_in,
                              void* d_out, int out_size, void* d_ws, size_t ws_size,
                              hipStream_t stream) {
    const int*   sid  = (const int*)d_in[0];
    const int*   eid  = (const int*)d_in[1];
    const int*   erow = (const int*)d_in[3];
    const int*   ecol = (const int*)d_in[4];
    const float* eval = (const float*)d_in[5];
    const float* stu  = (const float*)d_in[6];
    const float* exer = (const float*)d_in[7];
    const float* disc = (const float*)d_in[8];
    const float* know = (const float*)d_in[9];
    float* out = (float*)d_out;

    char* ws = (char*)d_ws;
    float* A       = (float*)(ws);                        // h1, 38.4 MB
    float* B       = (float*)(ws + NODE_BYTES);           // h2, 38.4 MB
    int*   off     = (int*)  (ws + 76800000);             // 600,004 B
    int*   deg     = (int*)  (ws + 77400064);             // 600,000 B
    int*   cur     = (int*)  (ws + 78000064);             // 600,000 B
    int*   bsum    = (int*)  (ws + 78600064);             // 2,344 B
    int*   bsumoff = (int*)  (ws + 78602432);             // 2,344 B
    int2*  sedge   = (int2*) (ws + 78604800);             // 9,600,000 B  (ends ~88.2 MB)

    const int BLK = 256;
    int edgeGrid = (N_EDGES + BLK - 1) / BLK;             // 4688
    int nodeWaveGrid = (N_NODES * 64 + BLK - 1) / BLK;    // 37500
    int outMainGrid = (2 * NB * 64) / BLK;                // 4096
    int outTailGrid = (NB + KNOW * DIM + BLK - 1) / BLK;  // 63

    // CSR build
    hipMemsetAsync(deg, 0, N_NODES * sizeof(int), stream);
    k_hist <<<edgeGrid, BLK, 0, stream>>>(erow, deg);
    k_scan1<<<NSCAN_BLOCKS, BLK, 0, stream>>>(deg, off, bsum);
    k_scan2<<<1, 1024, 0, stream>>>(bsum, bsumoff);
    k_scan3<<<NSCAN_BLOCKS, BLK, 0, stream>>>(off, cur, bsumoff);
    k_fill <<<edgeGrid, BLK, 0, stream>>>(erow, ecol, eval, cur, sedge);

    // Layers 1 and 2 (full node table)
    k_gather_l1<<<nodeWaveGrid, BLK, 0, stream>>>(off, sedge, stu, exer, A);
    k_gather   <<<nodeWaveGrid, BLK, 0, stream>>>(off, sedge, A, B);

    // Layer 3 fused into outputs (only the needed rows)
    k_out_main<<<outMainGrid, BLK, 0, stream>>>(sid, eid, off, sedge, stu, exer, A, B, out);
    k_out_tail<<<outTailGrid, BLK, 0, stream>>>(eid, disc, know, out);
}

// Round 3
// 286.866 us; speedup vs baseline: 2.9931x; 1.4390x over previous
//
#include <hip/hip_runtime.h>

// LightGCN extractor, round 3: CSR-gather with bf16 intermediate node tables
// (halves gather traffic + L2 footprint) and 4x unrolled gather loop for MLP
// (miss-level parallelism). Layer 3 fused into the output kernel.

#define STU 100000
#define EXER 50000
#define KNOW 123
#define DIM 64
#define N_NODES 150000
#define N_EDGES 1200000
#define NB 8192              // batch size for sid/eid
#define NSCAN_BLOCKS 586     // ceil(150000/256)

typedef unsigned short bfu;

static const long long NODE_F = (long long)N_NODES * DIM;            // 9.6M elems
static const size_t NODE_BYTES_BF = (size_t)NODE_F * sizeof(bfu);    // 19.2 MB

__device__ __forceinline__ bfu f2bf(float f) {
    unsigned int u = __float_as_uint(f);
    unsigned int r = (u + 0x7FFFu + ((u >> 16) & 1u)) >> 16;   // RNE
    return (bfu)r;
}
__device__ __forceinline__ float bf2f(bfu h) {
    return __uint_as_float((unsigned int)h << 16);
}

// ---- h0 concat -> bf16 table ----
__global__ void k_conv0(const float* __restrict__ stu, const float* __restrict__ exer,
                        bfu* __restrict__ b0) {
    long long i = (long long)blockIdx.x * blockDim.x + threadIdx.x;  // float4 index
    long long n4 = NODE_F >> 2;
    if (i >= n4) return;
    long long stu4 = ((long long)STU * DIM) >> 2;
    float4 v = (i < stu4) ? ((const float4*)stu)[i]
                          : ((const float4*)exer)[i - stu4];
    ushort4 o;
    o.x = f2bf(v.x); o.y = f2bf(v.y); o.z = f2bf(v.z); o.w = f2bf(v.w);
    ((ushort4*)b0)[i] = o;
}

// ---- CSR build ----
__global__ void k_hist(const int* __restrict__ erow, int* __restrict__ deg) {
    int e = blockIdx.x * blockDim.x + threadIdx.x;
    if (e < N_EDGES) atomicAdd(&deg[erow[e]], 1);
}

__global__ void k_scan1(const int* __restrict__ deg, int* __restrict__ off,
                        int* __restrict__ bsum) {
    __shared__ int s[256];
    int i = blockIdx.x * 256 + threadIdx.x;
    int v = (i < N_NODES) ? deg[i] : 0;
    s[threadIdx.x] = v;
    __syncthreads();
    for (int o = 1; o < 256; o <<= 1) {
        int x = (threadIdx.x >= o) ? s[threadIdx.x - o] : 0;
        __syncthreads();
        s[threadIdx.x] += x;
        __syncthreads();
    }
    if (i < N_NODES) off[i] = s[threadIdx.x] - v;
    if (threadIdx.x == 255) bsum[blockIdx.x] = s[255];
}

__global__ void k_scan2(const int* __restrict__ bsum, int* __restrict__ bsumoff) {
    __shared__ int s[1024];
    int t = threadIdx.x;
    int v = (t < NSCAN_BLOCKS) ? bsum[t] : 0;
    s[t] = v;
    __syncthreads();
    for (int o = 1; o < 1024; o <<= 1) {
        int x = (t >= o) ? s[t - o] : 0;
        __syncthreads();
        s[t] += x;
        __syncthreads();
    }
    if (t < NSCAN_BLOCKS) bsumoff[t] = s[t] - v;
}

__global__ void k_scan3(int* __restrict__ off, int* __restrict__ cur,
                        const int* __restrict__ bsumoff) {
    int i = blockIdx.x * 256 + threadIdx.x;
    if (i < N_NODES) {
        int v = off[i] + bsumoff[i >> 8];
        off[i] = v;
        cur[i] = v;
    }
    if (i == 0) off[N_NODES] = N_EDGES;
}

__global__ void k_fill(const int* __restrict__ erow, const int* __restrict__ ecol,
                       const float* __restrict__ eval,
                       int* __restrict__ cur, int2* __restrict__ sedge) {
    int e = blockIdx.x * blockDim.x + threadIdx.x;
    if (e < N_EDGES) {
        int r = erow[e];
        int p = atomicAdd(&cur[r], 1);
        sedge[p] = make_int2(ecol[e], __float_as_int(eval[e]));
    }
}

// ---- gather layer: wave per node, lane per dim, bf16 table in/out ----
__global__ void k_gather_bf(const int* __restrict__ off, const int2* __restrict__ sedge,
                            const bfu* __restrict__ h, bfu* __restrict__ out) {
    int w = (blockIdx.x * blockDim.x + threadIdx.x) >> 6;
    int lane = threadIdx.x & 63;
    if (w >= N_NODES) return;
    int s = off[w], e = off[w + 1];
    float acc = 0.f;
    int k = s;
    for (; k + 4 <= e; k += 4) {
        int2 e0 = sedge[k], e1 = sedge[k + 1], e2 = sedge[k + 2], e3 = sedge[k + 3];
        float a0 = bf2f(h[(long long)e0.x * DIM + lane]);
        float a1 = bf2f(h[(long long)e1.x * DIM + lane]);
        float a2 = bf2f(h[(long long)e2.x * DIM + lane]);
        float a3 = bf2f(h[(long long)e3.x * DIM + lane]);
        acc += __int_as_float(e0.y) * a0;
        acc += __int_as_float(e1.y) * a1;
        acc += __int_as_float(e2.y) * a2;
        acc += __int_as_float(e3.y) * a3;
    }
    for (; k < e; k++) {
        int2 ev = sedge[k];
        acc += __int_as_float(ev.y) * bf2f(h[(long long)ev.x * DIM + lane]);
    }
    out[(long long)w * DIM + lane] = f2bf(acc);
}

// ---- outputs: layer-3 gather over B2 fused, only at the 16K needed rows ----
// out layout: [0,524288) student_ts | [524288,1048576) diff_ts
//             [1048576,1056768) disc | [1056768,1064640) know
__global__ void k_out_main(const int* __restrict__ sid, const int* __restrict__ eid,
                           const int* __restrict__ off, const int2* __restrict__ sedge,
                           const float* __restrict__ stu, const float* __restrict__ exer,
                           const bfu* __restrict__ B1, const bfu* __restrict__ B2,
                           float* __restrict__ out) {
    int w = (blockIdx.x * blockDim.x + threadIdx.x) >> 6;
    int lane = threadIdx.x & 63;
    if (w >= 2 * NB) return;
    int r;
    long long obase;
    if (w < NB) { r = sid[w];             obase = (long long)w * 64; }
    else        { r = STU + eid[w - NB];  obase = 524288 + (long long)(w - NB) * 64; }
    long long rb = (long long)r * 64 + lane;
    float h0 = (r < STU) ? stu[rb] : exer[rb - (long long)STU * 64];
    float s = h0 + bf2f(B1[rb]) + bf2f(B2[rb]);
    int st = off[r], en = off[r + 1];
    float g = 0.f;
    int k = st;
    for (; k + 4 <= en; k += 4) {
        int2 e0 = sedge[k], e1 = sedge[k + 1], e2 = sedge[k + 2], e3 = sedge[k + 3];
        float a0 = bf2f(B2[(long long)e0.x * DIM + lane]);
        float a1 = bf2f(B2[(long long)e1.x * DIM + lane]);
        float a2 = bf2f(B2[(long long)e2.x * DIM + lane]);
        float a3 = bf2f(B2[(long long)e3.x * DIM + lane]);
        g += __int_as_float(e0.y) * a0;
        g += __int_as_float(e1.y) * a1;
        g += __int_as_float(e2.y) * a2;
        g += __int_as_float(e3.y) * a3;
    }
    for (; k < en; k++) {
        int2 ev = sedge[k];
        g += __int_as_float(ev.y) * bf2f(B2[(long long)ev.x * DIM + lane]);
    }
    out[obase + lane] = 0.25f * (s + g);
}

__global__ void k_out_tail(const int* __restrict__ eid, const float* __restrict__ disc,
                           const float* __restrict__ know, float* __restrict__ out) {
    int i = blockIdx.x * blockDim.x + threadIdx.x;
    if (i < NB) out[1048576 + i] = disc[eid[i]];
    else if (i < NB + KNOW * DIM) out[1056768 + (i - NB)] = know[i - NB];
}

extern "C" void kernel_launch(void* const* d_in, const int* in_sizes, int n_in,
                              void* d_out, int out_size, void* d_ws, size_t ws_size,
                              hipStream_t stream) {
    const int*   sid  = (const int*)d_in[0];
    const int*   eid  = (const int*)d_in[1];
    const int*   erow = (const int*)d_in[3];
    const int*   ecol = (const int*)d_in[4];
    const float* eval = (const float*)d_in[5];
    const float* stu  = (const float*)d_in[6];
    const float* exer = (const float*)d_in[7];
    const float* disc = (const float*)d_in[8];
    const float* know = (const float*)d_in[9];
    float* out = (float*)d_out;

    char* ws = (char*)d_ws;
    bfu*  B0      = (bfu*) (ws);                          // h0 bf16, 19.2 MB
    bfu*  B1      = (bfu*) (ws + 19200000);               // h1 bf16, 19.2 MB
    bfu*  B2      = (bfu*) (ws + 38400000);               // h2 bf16, 19.2 MB
    int*  off     = (int*) (ws + 57600000);               // 600,004 B
    int*  deg     = (int*) (ws + 58200064);               // 600,000 B
    int*  cur     = (int*) (ws + 58800128);               // 600,000 B
    int*  bsum    = (int*) (ws + 59400192);               // 2,344 B
    int*  bsumoff = (int*) (ws + 59402560);               // 2,344 B
    int2* sedge   = (int2*)(ws + 59404928);               // 9.6 MB (ends ~69 MB)

    const int BLK = 256;
    int edgeGrid = (N_EDGES + BLK - 1) / BLK;             // 4688
    long long n4 = NODE_F >> 2;
    int convGrid = (int)((n4 + BLK - 1) / BLK);           // 9375
    int nodeWaveGrid = (int)(((long long)N_NODES * 64 + BLK - 1) / BLK);  // 37500
    int outMainGrid = (2 * NB * 64) / BLK;                // 4096
    int outTailGrid = (NB + KNOW * DIM + BLK - 1) / BLK;  // 63

    // h0 -> bf16 table (overlaps CSR build in the pipeline)
    k_conv0<<<convGrid, BLK, 0, stream>>>(stu, exer, B0);

    // CSR build
    hipMemsetAsync(deg, 0, N_NODES * sizeof(int), stream);
    k_hist <<<edgeGrid, BLK, 0, stream>>>(erow, deg);
    k_scan1<<<NSCAN_BLOCKS, BLK, 0, stream>>>(deg, off, bsum);
    k_scan2<<<1, 1024, 0, stream>>>(bsum, bsumoff);
    k_scan3<<<NSCAN_BLOCKS, BLK, 0, stream>>>(off, cur, bsumoff);
    k_fill <<<edgeGrid, BLK, 0, stream>>>(erow, ecol, eval, cur, sedge);

    // Layers 1 and 2 (full node table, bf16)
    k_gather_bf<<<nodeWaveGrid, BLK, 0, stream>>>(off, sedge, B0, B1);
    k_gather_bf<<<nodeWaveGrid, BLK, 0, stream>>>(off, sedge, B1, B2);

    // Layer 3 fused into outputs (only the needed rows)
    k_out_main<<<outMainGrid, BLK, 0, stream>>>(sid, eid, off, sedge, stu, exer, B1, B2, out);
    k_out_tail<<<outTailGrid, BLK, 0, stream>>>(eid, disc, know, out);
}

// Round 4
// 226.683 us; speedup vs baseline: 3.7878x; 1.2655x over previous
//
#include <hip/hip_runtime.h>

// LightGCN extractor, round 4:
//  - XCD-sliced CSR fill + hist (writes/atomics stay in one XCD's L2)
//  - gather layers: wave-uniform scalar edge loads (s_load) + unroll 8
//  - bf16 intermediate tables, layer 3 fused into output kernel

#define STU 100000
#define EXER 50000
#define KNOW 123
#define DIM 64
#define N_NODES 150000
#define N_EDGES 1200000
#define NB 8192
#define NSCAN_BLOCKS 586     // ceil(150000/256)
#define NSLICE 8
#define ROWS_PER_SLICE 18750 // 150000/8
#define FILL_BLOCKS 2048     // 256 blocks per slice

typedef unsigned short bfu;

static const long long NODE_F = (long long)N_NODES * DIM;  // 9.6M elems

__device__ __forceinline__ bfu f2bf(float f) {
    unsigned int u = __float_as_uint(f);
    unsigned int r = (u + 0x7FFFu + ((u >> 16) & 1u)) >> 16;   // RNE
    return (bfu)r;
}
__device__ __forceinline__ float bf2f(bfu h) {
    return __uint_as_float((unsigned int)h << 16);
}

// ---- h0 concat -> bf16 table ----
__global__ void k_conv0(const float* __restrict__ stu, const float* __restrict__ exer,
                        bfu* __restrict__ b0) {
    long long i = (long long)blockIdx.x * blockDim.x + threadIdx.x;  // float4 index
    long long n4 = NODE_F >> 2;
    if (i >= n4) return;
    long long stu4 = ((long long)STU * DIM) >> 2;
    float4 v = (i < stu4) ? ((const float4*)stu)[i]
                          : ((const float4*)exer)[i - stu4];
    ushort4 o;
    o.x = f2bf(v.x); o.y = f2bf(v.y); o.z = f2bf(v.z); o.w = f2bf(v.w);
    ((ushort4*)b0)[i] = o;
}

// ---- CSR build (XCD-sliced) ----
__global__ void k_hist_sliced(const int* __restrict__ erow, int* __restrict__ deg) {
    int slice = blockIdx.x & (NSLICE - 1);
    int sb = blockIdx.x >> 3;
    int nb = gridDim.x >> 3;
    int lo = slice * ROWS_PER_SLICE, hi = lo + ROWS_PER_SLICE;
    long long per = (N_EDGES + nb - 1) / nb;
    long long s = (long long)sb * per;
    long long e = s + per; if (e > N_EDGES) e = N_EDGES;
    for (long long k = s + threadIdx.x; k < e; k += blockDim.x) {
        int r = erow[k];
        if (r >= lo && r < hi) atomicAdd(&deg[r], 1);
    }
}

__global__ void k_scan1(const int* __restrict__ deg, int* __restrict__ off,
                        int* __restrict__ bsum) {
    __shared__ int s[256];
    int i = blockIdx.x * 256 + threadIdx.x;
    int v = (i < N_NODES) ? deg[i] : 0;
    s[threadIdx.x] = v;
    __syncthreads();
    for (int o = 1; o < 256; o <<= 1) {
        int x = (threadIdx.x >= o) ? s[threadIdx.x - o] : 0;
        __syncthreads();
        s[threadIdx.x] += x;
        __syncthreads();
    }
    if (i < N_NODES) off[i] = s[threadIdx.x] - v;
    if (threadIdx.x == 255) bsum[blockIdx.x] = s[255];
}

__global__ void k_scan2(const int* __restrict__ bsum, int* __restrict__ bsumoff) {
    __shared__ int s[1024];
    int t = threadIdx.x;
    int v = (t < NSCAN_BLOCKS) ? bsum[t] : 0;
    s[t] = v;
    __syncthreads();
    for (int o = 1; o < 1024; o <<= 1) {
        int x = (t >= o) ? s[t - o] : 0;
        __syncthreads();
        s[t] += x;
        __syncthreads();
    }
    if (t < NSCAN_BLOCKS) bsumoff[t] = s[t] - v;
}

__global__ void k_scan3(int* __restrict__ off, int* __restrict__ cur,
                        const int* __restrict__ bsumoff) {
    int i = blockIdx.x * 256 + threadIdx.x;
    if (i < N_NODES) {
        int v = off[i] + bsumoff[i >> 8];
        off[i] = v;
        cur[i] = v;
    }
    if (i == 0) off[N_NODES] = N_EDGES;
}

__global__ void k_fill_sliced(const int* __restrict__ erow, const int* __restrict__ ecol,
                              const float* __restrict__ eval,
                              int* __restrict__ cur, int2* __restrict__ sedge) {
    int slice = blockIdx.x & (NSLICE - 1);
    int sb = blockIdx.x >> 3;
    int nb = gridDim.x >> 3;
    int lo = slice * ROWS_PER_SLICE, hi = lo + ROWS_PER_SLICE;
    long long per = (N_EDGES + nb - 1) / nb;
    long long s = (long long)sb * per;
    long long e = s + per; if (e > N_EDGES) e = N_EDGES;
    for (long long k = s + threadIdx.x; k < e; k += blockDim.x) {
        int r = erow[k];
        if (r >= lo && r < hi) {
            int p = atomicAdd(&cur[r], 1);
            sedge[p] = make_int2(ecol[k], __float_as_int(eval[k]));
        }
    }
}

// ---- gather layer: wave per node, lane per dim, bf16 in/out ----
__global__ void k_gather_bf(const int* __restrict__ off, const int2* __restrict__ sedge,
                            const bfu* __restrict__ h, bfu* __restrict__ out) {
    int w = (blockIdx.x * blockDim.x + threadIdx.x) >> 6;
    int lane = threadIdx.x & 63;
    if (w >= N_NODES) return;
    int wu = __builtin_amdgcn_readfirstlane(w);          // wave-uniform -> s_load path
    int s = off[wu], e = off[wu + 1];
    float acc = 0.f;
    int k = s;
    for (; k + 8 <= e; k += 8) {
        int2 ev[8];
#pragma unroll
        for (int j = 0; j < 8; j++) ev[j] = sedge[k + j];
        float a[8];
#pragma unroll
        for (int j = 0; j < 8; j++) a[j] = bf2f(h[(long long)ev[j].x * DIM + lane]);
#pragma unroll
        for (int j = 0; j < 8; j++) acc += __int_as_float(ev[j].y) * a[j];
    }
    for (; k + 4 <= e; k += 4) {
        int2 ev[4];
#pragma unroll
        for (int j = 0; j < 4; j++) ev[j] = sedge[k + j];
        float a[4];
#pragma unroll
        for (int j = 0; j < 4; j++) a[j] = bf2f(h[(long long)ev[j].x * DIM + lane]);
#pragma unroll
        for (int j = 0; j < 4; j++) acc += __int_as_float(ev[j].y) * a[j];
    }
    for (; k < e; k++) {
        int2 ev = sedge[k];
        acc += __int_as_float(ev.y) * bf2f(h[(long long)ev.x * DIM + lane]);
    }
    out[(long long)wu * DIM + lane] = f2bf(acc);
}

// ---- outputs: layer-3 gather over B2 fused, only at the 16K needed rows ----
__global__ void k_out_main(const int* __restrict__ sid, const int* __restrict__ eid,
                           const int* __restrict__ off, const int2* __restrict__ sedge,
                           const float* __restrict__ stu, const float* __restrict__ exer,
                           const bfu* __restrict__ B1, const bfu* __restrict__ B2,
                           float* __restrict__ out) {
    int w = (blockIdx.x * blockDim.x + threadIdx.x) >> 6;
    int lane = threadIdx.x & 63;
    if (w >= 2 * NB) return;
    int wu = __builtin_amdgcn_readfirstlane(w);
    int r;
    long long obase;
    if (wu < NB) { r = sid[wu];            obase = (long long)wu * 64; }
    else         { r = STU + eid[wu - NB]; obase = 524288 + (long long)(wu - NB) * 64; }
    int ru = __builtin_amdgcn_readfirstlane(r);
    long long rb = (long long)ru * 64 + lane;
    float h0 = (ru < STU) ? stu[rb] : exer[rb - (long long)STU * 64];
    float s = h0 + bf2f(B1[rb]) + bf2f(B2[rb]);
    int st = off[ru], en = off[ru + 1];
    float g = 0.f;
    int k = st;
    for (; k + 8 <= en; k += 8) {
        int2 ev[8];
#pragma unroll
        for (int j = 0; j < 8; j++) ev[j] = sedge[k + j];
        float a[8];
#pragma unroll
        for (int j = 0; j < 8; j++) a[j] = bf2f(B2[(long long)ev[j].x * DIM + lane]);
#pragma unroll
        for (int j = 0; j < 8; j++) g += __int_as_float(ev[j].y) * a[j];
    }
    for (; k < en; k++) {
        int2 ev = sedge[k];
        g += __int_as_float(ev.y) * bf2f(B2[(long long)ev.x * DIM + lane]);
    }
    out[obase + lane] = 0.25f * (s + g);
}

__global__ void k_out_tail(const int* __restrict__ eid, const float* __restrict__ disc,
                           const float* __restrict__ know, float* __restrict__ out) {
    int i = blockIdx.x * blockDim.x + threadIdx.x;
    if (i < NB) out[1048576 + i] = disc[eid[i]];
    else if (i < NB + KNOW * DIM) out[1056768 + (i - NB)] = know[i - NB];
}

extern "C" void kernel_launch(void* const* d_in, const int* in_sizes, int n_in,
                              void* d_out, int out_size, void* d_ws, size_t ws_size,
                              hipStream_t stream) {
    const int*   sid  = (const int*)d_in[0];
    const int*   eid  = (const int*)d_in[1];
    const int*   erow = (const int*)d_in[3];
    const int*   ecol = (const int*)d_in[4];
    const float* eval = (const float*)d_in[5];
    const float* stu  = (const float*)d_in[6];
    const float* exer = (const float*)d_in[7];
    const float* disc = (const float*)d_in[8];
    const float* know = (const float*)d_in[9];
    float* out = (float*)d_out;

    char* ws = (char*)d_ws;
    bfu*  B0      = (bfu*) (ws);                          // h0 bf16, 19.2 MB
    bfu*  B1      = (bfu*) (ws + 19200000);               // h1 bf16, 19.2 MB
    bfu*  B2      = (bfu*) (ws + 38400000);               // h2 bf16, 19.2 MB
    int*  off     = (int*) (ws + 57600000);               // 600,004 B
    int*  deg     = (int*) (ws + 58200064);               // 600,000 B
    int*  cur     = (int*) (ws + 58800128);               // 600,000 B
    int*  bsum    = (int*) (ws + 59400192);               // 2,344 B
    int*  bsumoff = (int*) (ws + 59402560);               // 2,344 B
    int2* sedge   = (int2*)(ws + 59404928);               // 9.6 MB (ends ~69 MB)

    const int BLK = 256;
    long long n4 = NODE_F >> 2;
    int convGrid = (int)((n4 + BLK - 1) / BLK);           // 9375
    int nodeWaveGrid = (int)(((long long)N_NODES * 64 + BLK - 1) / BLK);  // 37500
    int outMainGrid = (2 * NB * 64) / BLK;                // 4096
    int outTailGrid = (NB + KNOW * DIM + BLK - 1) / BLK;  // 63

    // h0 -> bf16 table
    k_conv0<<<convGrid, BLK, 0, stream>>>(stu, exer, B0);

    // CSR build (XCD-sliced hist/fill)
    hipMemsetAsync(deg, 0, N_NODES * sizeof(int), stream);
    k_hist_sliced<<<FILL_BLOCKS, BLK, 0, stream>>>(erow, deg);
    k_scan1<<<NSCAN_BLOCKS, BLK, 0, stream>>>(deg, off, bsum);
    k_scan2<<<1, 1024, 0, stream>>>(bsum, bsumoff);
    k_scan3<<<NSCAN_BLOCKS, BLK, 0, stream>>>(off, cur, bsumoff);
    k_fill_sliced<<<FILL_BLOCKS, BLK, 0, stream>>>(erow, ecol, eval, cur, sedge);

    // Layers 1 and 2 (full node table, bf16)
    k_gather_bf<<<nodeWaveGrid, BLK, 0, stream>>>(off, sedge, B0, B1);
    k_gather_bf<<<nodeWaveGrid, BLK, 0, stream>>>(off, sedge, B1, B2);

    // Layer 3 fused into outputs
    k_out_main<<<outMainGrid, BLK, 0, stream>>>(sid, eid, off, sedge, stu, exer, B1, B2, out);
    k_out_tail<<<outTailGrid, BLK, 0, stream>>>(eid, disc, know, out);
}